// Round 14
// baseline (268.439 us; speedup 1.0000x reference)
//
#include <hip/hip_runtime.h>
#include <hip/hip_bf16.h>
#include <cstdint>

// MoE SwiGLU: E=8 experts, top-2, D=1024, H=2048, T=4096 tokens.
// Round 14: 256-row tiles with whole-tile depth-1 prefetch: per K-tile,
// {vmcnt(0) on loads issued ONE FULL TILE earlier -> barrier -> issue next
// tile into other slot -> 64 MFMA}. Fixes round-13's NaN (phase gates didn't
// cover the rows each wave actually reads). gemm1 BN=256={W0,W1} interleaved
// per 32 cols (SwiGLU lane-local); gemm2 same skeleton.

#define E_ 8
#define D_ 1024
#define H_ 2048
#define T_ 4096

typedef __attribute__((ext_vector_type(8))) __bf16 bf16x8;
typedef __attribute__((ext_vector_type(4))) float f32x4;
typedef unsigned short u16;
typedef __attribute__((ext_vector_type(4))) u16 u16x4;

__device__ __forceinline__ u16 f2b(float f) {
    union { float f; unsigned int u; } v; v.f = f;
    unsigned int u = v.u;
    return (u16)((u + 0x7FFFu + ((u >> 16) & 1u)) >> 16);  // RNE
}

__device__ __forceinline__ float b2f(u16 v) {
    union { unsigned int u; float f; } x; x.u = (unsigned int)v << 16; return x.f;
}

__device__ __forceinline__ void gld16(const void* g, void* l) {
    __builtin_amdgcn_global_load_lds((const __attribute__((address_space(1))) void*)g,
                                     (__attribute__((address_space(3))) void*)l, 16, 0, 0);
}

// ---- gate: 1 token/wave; gw LDS-cached; chunked counters (64 cache lines) ----
__global__ void k_gate(const float* __restrict__ x, const float* __restrict__ gw,
                       int* __restrict__ cnt2, int4* __restrict__ tslot,
                       float2* __restrict__ twgt, u16* __restrict__ xb) {
    __shared__ float gws[E_ * D_];  // 32 KB
    int tid = threadIdx.x;
#pragma unroll
    for (int p = 0; p < 8; ++p) {
        int i = (p * 256 + tid) * 4;
        *(float4*)&gws[i] = *(const float4*)&gw[i];
    }
    __syncthreads();
    int wid = tid >> 6, lane = tid & 63;
    int t = blockIdx.x * 4 + wid;
    int chunk = blockIdx.x & 63;
    const float* xr = x + (size_t)t * D_;
    float part[E_];
#pragma unroll
    for (int e = 0; e < E_; ++e) part[e] = 0.f;
#pragma unroll
    for (int i = 0; i < 4; ++i) {
        int d = i * 256 + lane * 4;
        float4 xv = *(const float4*)(xr + d);
        u16x4 o;
        o[0] = f2b(xv.x); o[1] = f2b(xv.y); o[2] = f2b(xv.z); o[3] = f2b(xv.w);
        *(u16x4*)(xb + (size_t)t * D_ + d) = o;
#pragma unroll
        for (int e = 0; e < E_; ++e) {
            float4 g = *(const float4*)&gws[e * D_ + d];
            part[e] += xv.x * g.x + xv.y * g.y + xv.z * g.z + xv.w * g.w;
        }
    }
#pragma unroll
    for (int off = 32; off >= 1; off >>= 1) {
#pragma unroll
        for (int e = 0; e < E_; ++e) part[e] += __shfl_xor(part[e], off);
    }
    if (lane == 0) {
        int e0 = 0; float m0 = part[0];
#pragma unroll
        for (int e = 1; e < E_; ++e) if (part[e] > m0) { m0 = part[e]; e0 = e; }
        int e1 = -1; float m1 = -3.4e38f;
#pragma unroll
        for (int e = 0; e < E_; ++e) if (e != e0 && part[e] > m1) { m1 = part[e]; e1 = e; }
        float sx = __expf(m1 - m0);
        float w0 = 1.f / (1.f + sx);
        float w1 = sx / (1.f + sx);
        int lp0 = atomicAdd(&cnt2[chunk * 16 + e0], 1);  // 16-int stride: 1 line/chunk
        int lp1 = atomicAdd(&cnt2[chunk * 16 + e1], 1);
        tslot[t] = make_int4(e0, lp0, e1, lp1);          // local record; fixup globalizes
        twgt[t] = make_float2(w0, w1);
    }
}

// ---- scan2: per-expert chunk prefix (exclusive), offs, cnt ----
__global__ void k_scan2(const int* __restrict__ cnt2, int* __restrict__ chunk_off,
                        int* __restrict__ cnt, int* __restrict__ offs) {
    __shared__ int totals[E_];
    int e = threadIdx.x >> 6, lane = threadIdx.x & 63;   // wave = expert
    int v = cnt2[lane * 16 + e];
    int incl = v;
#pragma unroll
    for (int d = 1; d < 64; d <<= 1) {
        int u = __shfl_up(incl, d);
        if (lane >= d) incl += u;
    }
    int excl = incl - v;
    if (lane == 63) totals[e] = incl;
    __syncthreads();
    chunk_off[lane * 8 + e] = excl;        // per-expert position base
    if (lane == 0) {
        int off_e = 0;
        for (int q = 0; q < e; ++q) off_e += totals[q];
        offs[e] = off_e; cnt[e] = totals[e];
    }
}

// ---- fixup: local slot -> per-expert slot; build tok lists ----
__global__ void k_fixup(const int* __restrict__ chunk_off, int4* __restrict__ tslot,
                        int* __restrict__ tok) {
    int t = blockIdx.x * 256 + threadIdx.x;
    int chunk = (t >> 2) & 63;
    int4 r = tslot[t];
    int s0 = chunk_off[chunk * 8 + r.x] + r.y;   // per-expert slot, < cnt[e]
    int s1 = chunk_off[chunk * 8 + r.z] + r.w;
    tok[r.x * T_ + s0] = t;
    tok[r.z * T_ + s1] = t;
    tslot[t] = make_int4(r.x, s0, r.z, s1);
}

// ---- merged transpose: fp32 [R][C] -> bf16 [C][R]; z = which*8 + e ----
__global__ void k_transpose_all(const float* __restrict__ W0, const float* __restrict__ W1,
                                const float* __restrict__ W2, u16* __restrict__ w0t,
                                u16* __restrict__ w1t, u16* __restrict__ w2t) {
    __shared__ float tile[64][67];
    int z = blockIdx.z, which = z >> 3, e = z & 7;
    const float* src; u16* dst; int R, C, c0, r0;
    if (which == 0)      { src = W0 + (size_t)e * D_ * H_; dst = w0t + (size_t)e * D_ * H_;
                           R = D_; C = H_; c0 = blockIdx.x * 64; r0 = blockIdx.y * 64; }
    else if (which == 1) { src = W1 + (size_t)e * D_ * H_; dst = w1t + (size_t)e * D_ * H_;
                           R = D_; C = H_; c0 = blockIdx.x * 64; r0 = blockIdx.y * 64; }
    else                 { src = W2 + (size_t)e * H_ * D_; dst = w2t + (size_t)e * H_ * D_;
                           R = H_; C = D_; c0 = blockIdx.y * 64; r0 = blockIdx.x * 64; }
    int tc4 = (threadIdx.x & 15) * 4, tr = threadIdx.x >> 4;
#pragma unroll
    for (int p = 0; p < 4; ++p) {
        float4 v = *(const float4*)(src + (size_t)(r0 + tr + 16 * p) * C + c0 + tc4);
        tile[tr + 16 * p][tc4 + 0] = v.x;
        tile[tr + 16 * p][tc4 + 1] = v.y;
        tile[tr + 16 * p][tc4 + 2] = v.z;
        tile[tr + 16 * p][tc4 + 3] = v.w;
    }
    __syncthreads();
    int r4 = (threadIdx.x & 15) * 4, tc = threadIdx.x >> 4;
#pragma unroll
    for (int p = 0; p < 4; ++p) {
        int c = tc + 16 * p;
        u16x4 o;
#pragma unroll
        for (int j = 0; j < 4; ++j) o[j] = f2b(tile[r4 + j][c]);
        *(u16x4*)(dst + (size_t)(c0 + c) * R + r0 + r4) = o;
    }
}

// ---- GEMM1: BM=256 gathered rows, BN=256 = 128 hcols x {W0,W1} interleaved
//      per 32 cols; depth-1 whole-tile prefetch, 2x64KB slots. 8 waves 2Mx4N. ----
__launch_bounds__(512, 2)
__global__ void k_gemm1(const u16* __restrict__ xb, const u16* __restrict__ w0t,
                        const u16* __restrict__ w1t, const float* __restrict__ b0,
                        const float* __restrict__ b1, const int* __restrict__ tok,
                        const int* __restrict__ cnt, const int* __restrict__ offs,
                        u16* __restrict__ gbuf) {
    int e = blockIdx.z, rt = blockIdx.y, ct = blockIdx.x;
    int cN = cnt[e];
    if (rt * 256 >= cN) return;
    __shared__ char lds[131072];  // slot s @ s*65536: A[256][64] @0, B[256][64] @32768
    int tid = threadIdx.x, wid = tid >> 6, lane = tid & 63;
    int wm = wid >> 2, wn = wid & 3;  // per-wave output: 128 rows x 64 cols
    const int* tokE = tok + e * T_;
    const u16* w0e = w0t + (size_t)e * H_ * D_;
    size_t wdelta = (size_t)(w1t - w0t);  // w1e = w0e + wdelta

    unsigned aoff[4]; int adst[4]; size_t boff[4];
#pragma unroll
    for (int i = 0; i < 4; ++i) {
        int cid = i * 512 + tid;
        int r = cid >> 3, c = cid & 7, cc = c ^ (r & 7);
        int tk = tokE[min(rt * 256 + r, cN - 1)];
        aoff[i] = (unsigned)(tk * D_ + cc * 8);
        adst[i] = (i * 512 + wid * 64) * 16;   // linear wave-uniform dest
        // B rows: group g=r>>5, which=g&1 (W0/W1), hcol = ct*128+(g>>1)*32+(r&31)
        int g = r >> 5, which = g & 1;
        int hcol = ct * 128 + (g >> 1) * 32 + (r & 31);
        boff[i] = (size_t)which * wdelta + (size_t)hcol * D_ + cc * 8;
    }

    auto stageAll = [&](char* slot, int k0) {  // 8 VMEM per thread
#pragma unroll
        for (int i = 0; i < 4; ++i) gld16(xb + aoff[i] + k0, slot + adst[i]);
#pragma unroll
        for (int i = 0; i < 4; ++i) gld16(w0e + boff[i] + k0, slot + 32768 + adst[i]);
    };

    f32x4 acc[8][4];
#pragma unroll
    for (int m = 0; m < 8; ++m)
#pragma unroll
        for (int n = 0; n < 4; ++n) acc[m][n] = (f32x4)0.f;

    const int NT = D_ / 64;
    stageAll(lds, 0);  // tile 0 -> slot 0
    for (int t = 0; t < NT; ++t) {
        asm volatile("s_waitcnt vmcnt(0)" ::: "memory");  // tile t's loads (issued 1 tile ago)
        __builtin_amdgcn_s_barrier();                      // all waves: tile t ready, slot t+1 free
        const char* As = lds + (t & 1) * 65536;
        const char* Bs = As + 32768;
        if (t + 1 < NT) stageAll(lds + ((t + 1) & 1) * 65536, (t + 1) * 64);
        // B fragments once (reused across MH)
        bf16x8 bfr[2][4];
#pragma unroll
        for (int ks = 0; ks < 2; ++ks) {
            int kc = ks * 4 + (lane >> 4);
#pragma unroll
            for (int q = 0; q < 4; ++q) {
                int rb = wn * 64 + q * 16 + (lane & 15);
                bfr[ks][q] = *(const bf16x8*)(Bs + rb * 128 + ((kc ^ (rb & 7)) << 4));
            }
        }
#pragma unroll
        for (int MH = 0; MH < 2; ++MH) {
            bf16x8 afr[2][4];
#pragma unroll
            for (int ks = 0; ks < 2; ++ks) {
                int kc = ks * 4 + (lane >> 4);
#pragma unroll
                for (int m = 0; m < 4; ++m) {
                    int row = wm * 128 + MH * 64 + m * 16 + (lane & 15);
                    afr[ks][m] = *(const bf16x8*)(As + row * 128 + ((kc ^ (row & 7)) << 4));
                }
            }
            __builtin_amdgcn_s_setprio(1);
#pragma unroll
            for (int ks = 0; ks < 2; ++ks)
#pragma unroll
                for (int m = 0; m < 4; ++m)
#pragma unroll
                    for (int q = 0; q < 4; ++q)
                        acc[MH * 4 + m][q] = __builtin_amdgcn_mfma_f32_16x16x32_bf16(
                            afr[ks][m], bfr[ks][q], acc[MH * 4 + m][q], 0, 0, 0);
            __builtin_amdgcn_s_setprio(0);
        }
    }

    int off_e = offs[e];
#pragma unroll
    for (int n = 0; n < 2; ++n) {
        int hc = ct * 128 + wn * 32 + n * 16 + (lane & 15);
        float bb0 = b0[e * H_ + hc], bb1 = b1[e * H_ + hc];
#pragma unroll
        for (int mi = 0; mi < 8; ++mi)
#pragma unroll
            for (int i = 0; i < 4; ++i) {
                int idx = rt * 256 + wm * 128 + mi * 16 + (lane >> 4) * 4 + i;
                if (idx < cN) {
                    float h0 = acc[mi][n][i] + bb0;      // W0 cols (frags 0-1)
                    float h1 = acc[mi][n + 2][i] + bb1;  // W1 cols (frags 2-3)
                    float g = h0 * h1 / (1.f + __expf(-h1));
                    gbuf[(size_t)(off_e + idx) * H_ + hc] = f2b(g);
                }
            }
    }
}

// ---- GEMM2: BM=256, BN=128, depth-1 whole-tile prefetch, 2x48KB slots ----
__launch_bounds__(512, 2)
__global__ void k_gemm2(const u16* __restrict__ gbuf, const u16* __restrict__ w2t,
                        const float* __restrict__ b2, const int* __restrict__ cnt,
                        const int* __restrict__ offs, u16* __restrict__ yb) {
    int e = blockIdx.z, rt = blockIdx.y, ct = blockIdx.x;
    int cN = cnt[e];
    if (rt * 256 >= cN) return;
    __shared__ char lds[98304];  // slot s @ s*49152: A[256][64] @0, B[128][64] @32768
    int tid = threadIdx.x, wid = tid >> 6, lane = tid & 63;
    int wm = wid >> 2, wn = wid & 3;  // per-wave output: 128 rows x 32 cols
    int off_e = offs[e];
    const u16* Ag = gbuf + (size_t)(off_e + rt * 256) * H_;  // padded tail allows over-read
    const u16* Bw = w2t + (size_t)e * D_ * H_ + (size_t)(ct * 128) * H_;

    unsigned aoff[4]; int adst[4];
#pragma unroll
    for (int i = 0; i < 4; ++i) {
        int cid = i * 512 + tid, r = cid >> 3, c = cid & 7, cc = c ^ (r & 7);
        aoff[i] = (unsigned)(r * H_ + cc * 8);
        adst[i] = (i * 512 + wid * 64) * 16;
    }
    unsigned boff[2]; int bdst[2];
#pragma unroll
    for (int i = 0; i < 2; ++i) {
        int cid = i * 512 + tid, r = cid >> 3, c = cid & 7, cc = c ^ (r & 7);
        boff[i] = (unsigned)(r * H_ + cc * 8);
        bdst[i] = (i * 512 + wid * 64) * 16;
    }

    auto stageAll = [&](char* slot, int k0) {  // 6 VMEM per thread
#pragma unroll
        for (int i = 0; i < 4; ++i) gld16(Ag + aoff[i] + k0, slot + adst[i]);
#pragma unroll
        for (int i = 0; i < 2; ++i) gld16(Bw + boff[i] + k0, slot + 32768 + bdst[i]);
    };

    f32x4 acc[8][2];
#pragma unroll
    for (int m = 0; m < 8; ++m)
#pragma unroll
        for (int n = 0; n < 2; ++n) acc[m][n] = (f32x4)0.f;

    const int NT = H_ / 64;
    stageAll(lds, 0);
    for (int t = 0; t < NT; ++t) {
        asm volatile("s_waitcnt vmcnt(0)" ::: "memory");
        __builtin_amdgcn_s_barrier();
        const char* As = lds + (t & 1) * 49152;
        const char* Bs = As + 32768;
        if (t + 1 < NT) stageAll(lds + ((t + 1) & 1) * 49152, (t + 1) * 64);
        bf16x8 bfr[2][2];
#pragma unroll
        for (int ks = 0; ks < 2; ++ks) {
            int kc = ks * 4 + (lane >> 4);
#pragma unroll
            for (int q = 0; q < 2; ++q) {
                int rb = wn * 32 + q * 16 + (lane & 15);
                bfr[ks][q] = *(const bf16x8*)(Bs + rb * 128 + ((kc ^ (rb & 7)) << 4));
            }
        }
#pragma unroll
        for (int MH = 0; MH < 2; ++MH) {
            bf16x8 afr[2][4];
#pragma unroll
            for (int ks = 0; ks < 2; ++ks) {
                int kc = ks * 4 + (lane >> 4);
#pragma unroll
                for (int m = 0; m < 4; ++m) {
                    int row = wm * 128 + MH * 64 + m * 16 + (lane & 15);
                    afr[ks][m] = *(const bf16x8*)(As + row * 128 + ((kc ^ (row & 7)) << 4));
                }
            }
            __builtin_amdgcn_s_setprio(1);
#pragma unroll
            for (int ks = 0; ks < 2; ++ks)
#pragma unroll
                for (int m = 0; m < 4; ++m)
#pragma unroll
                    for (int q = 0; q < 2; ++q)
                        acc[MH * 4 + m][q] = __builtin_amdgcn_mfma_f32_16x16x32_bf16(
                            afr[ks][m], bfr[ks][q], acc[MH * 4 + m][q], 0, 0, 0);
            __builtin_amdgcn_s_setprio(0);
        }
    }

    const float* b2e = b2 + e * D_;
#pragma unroll
    for (int q = 0; q < 2; ++q) {
        int dc = ct * 128 + wn * 32 + q * 16 + (lane & 15);
        float bb = b2e[dc];
#pragma unroll
        for (int mi = 0; mi < 8; ++mi)
#pragma unroll
            for (int i = 0; i < 4; ++i) {
                int idx = rt * 256 + wm * 128 + mi * 16 + (lane >> 4) * 4 + i;
                if (idx < cN)
                    yb[(size_t)(off_e + idx) * D_ + dc] = f2b(acc[mi][q][i] + bb);
            }
    }
}

// ---- combine: out[t] = w0*y[offs[e0]+slot0] + w1*y[offs[e1]+slot1] ----
__global__ void k_combine(const u16* __restrict__ yb, const int4* __restrict__ tslot,
                          const float2* __restrict__ twgt, const int* __restrict__ offs,
                          float* __restrict__ out) {
    int t = blockIdx.x, d4 = threadIdx.x * 4;
    int4 s = tslot[t];
    float2 w = twgt[t];
    const u16* y0 = yb + (size_t)(offs[s.x] + s.y) * D_ + d4;
    const u16* y1 = yb + (size_t)(offs[s.z] + s.w) * D_ + d4;
    u16x4 a = *(const u16x4*)y0;
    u16x4 b = *(const u16x4*)y1;
    float4 o;
    o.x = w.x * b2f(a[0]) + w.y * b2f(b[0]);
    o.y = w.x * b2f(a[1]) + w.y * b2f(b[1]);
    o.z = w.x * b2f(a[2]) + w.y * b2f(b[2]);
    o.w = w.x * b2f(a[3]) + w.y * b2f(b[3]);
    *(float4*)(out + (size_t)t * D_ + d4) = o;
}

extern "C" void kernel_launch(void* const* d_in, const int* in_sizes, int n_in,
                              void* d_out, int out_size, void* d_ws, size_t ws_size,
                              hipStream_t stream) {
    const float* x  = (const float*)d_in[0];
    const float* gw = (const float*)d_in[1];
    const float* W0 = (const float*)d_in[2];
    const float* b0 = (const float*)d_in[3];
    const float* W1 = (const float*)d_in[4];
    const float* b1 = (const float*)d_in[5];
    const float* W2 = (const float*)d_in[6];
    const float* b2 = (const float*)d_in[7];
    float* out = (float*)d_out;

    char* ws = (char*)d_ws;
    size_t off = 0;
    u16* xb   = (u16*)(ws + off); off += (size_t)T_ * D_ * 2;             // 8 MB
    u16* w0t  = (u16*)(ws + off); off += (size_t)E_ * H_ * D_ * 2;        // 32 MB
    u16* w1t  = (u16*)(ws + off); off += (size_t)E_ * H_ * D_ * 2;        // 32 MB (contiguous after w0t)
    u16* w2t  = (u16*)(ws + off); off += (size_t)E_ * D_ * H_ * 2;        // 32 MB
    u16* gbuf = (u16*)(ws + off); off += (size_t)(T_ * 2 + 256) * H_ * 2; // padded tail
    int*   tok   = (int*)(ws + off);    off += (size_t)E_ * T_ * 4;
    int4*  tslot = (int4*)(ws + off);   off += (size_t)T_ * 16;
    float2* twgt = (float2*)(ws + off); off += (size_t)T_ * 8;
    int*   cnt2  = (int*)(ws + off);    off += 64 * 16 * 4;   // 64 chunks x 1 line
    int*   choff = (int*)(ws + off);    off += 64 * 8 * 4;
    int*   cnt   = (int*)(ws + off);    off += 64;
    int*   offs  = (int*)(ws + off);    off += 64;
    // y reuses w0t's region (dead after gemm1; gemm2 runs strictly after gemm1)
    u16* yb = w0t;  // needs (2T+256)*D*2 = 17 MB <= 32 MB

    if (ws_size < off) return;  // workspace too small: leave output poisoned (visible failure)
    hipMemsetAsync(cnt2, 0, 64 * 16 * 4, stream);

    k_gate<<<T_ / 4, 256, 0, stream>>>(x, gw, cnt2, tslot, twgt, xb);
    k_scan2<<<1, 512, 0, stream>>>(cnt2, choff, cnt, offs);
    k_fixup<<<T_ / 256, 256, 0, stream>>>(choff, tslot, tok);
    k_transpose_all<<<dim3(32, 16, 24), 256, 0, stream>>>(W0, W1, W2, w0t, w1t, w2t);
    k_gemm1<<<dim3(H_ / 128, T_ / 256, E_), 512, 0, stream>>>(xb, w0t, w1t, b0, b1, tok, cnt, offs, gbuf);
    k_gemm2<<<dim3(D_ / 128, T_ / 256, E_), 512, 0, stream>>>(gbuf, w2t, b2, cnt, offs, yb);
    k_combine<<<T_, 256, 0, stream>>>(yb, tslot, twgt, offs, out);
}

// Round 15
// 251.063 us; speedup vs baseline: 1.0692x; 1.0692x over previous
//
#include <hip/hip_runtime.h>
#include <hip/hip_bf16.h>
#include <cstdint>

// MoE SwiGLU: E=8 experts, top-2, D=1024, H=2048, T=4096 tokens.
// Round 15: gemm1 = r14's VALIDATED 256x256 layout (B = {W0,W1} interleaved
// per 32 cols) rescheduled into 4 fine phases/K-tile: each phase
// {frag ds_reads || stage ONE group of tile t+1 -> vmcnt(4) entry gates}.
// Stage groups == reader sets by construction. gemm2 + rest = round 12.

#define E_ 8
#define D_ 1024
#define H_ 2048
#define T_ 4096

typedef __attribute__((ext_vector_type(8))) __bf16 bf16x8;
typedef __attribute__((ext_vector_type(4))) float f32x4;
typedef unsigned short u16;
typedef __attribute__((ext_vector_type(4))) u16 u16x4;

__device__ __forceinline__ u16 f2b(float f) {
    union { float f; unsigned int u; } v; v.f = f;
    unsigned int u = v.u;
    return (u16)((u + 0x7FFFu + ((u >> 16) & 1u)) >> 16);  // RNE
}

__device__ __forceinline__ float b2f(u16 v) {
    union { unsigned int u; float f; } x; x.u = (unsigned int)v << 16; return x.f;
}

__device__ __forceinline__ void gld16(const void* g, void* l) {
    __builtin_amdgcn_global_load_lds((const __attribute__((address_space(1))) void*)g,
                                     (__attribute__((address_space(3))) void*)l, 16, 0, 0);
}

// ---- gate: 1 token/wave; gw LDS-cached; chunked counters (64 cache lines) ----
__global__ void k_gate(const float* __restrict__ x, const float* __restrict__ gw,
                       int* __restrict__ cnt2, int4* __restrict__ tslot,
                       float2* __restrict__ twgt, u16* __restrict__ xb) {
    __shared__ float gws[E_ * D_];  // 32 KB
    int tid = threadIdx.x;
#pragma unroll
    for (int p = 0; p < 8; ++p) {
        int i = (p * 256 + tid) * 4;
        *(float4*)&gws[i] = *(const float4*)&gw[i];
    }
    __syncthreads();
    int wid = tid >> 6, lane = tid & 63;
    int t = blockIdx.x * 4 + wid;
    int chunk = blockIdx.x & 63;
    const float* xr = x + (size_t)t * D_;
    float part[E_];
#pragma unroll
    for (int e = 0; e < E_; ++e) part[e] = 0.f;
#pragma unroll
    for (int i = 0; i < 4; ++i) {
        int d = i * 256 + lane * 4;
        float4 xv = *(const float4*)(xr + d);
        u16x4 o;
        o[0] = f2b(xv.x); o[1] = f2b(xv.y); o[2] = f2b(xv.z); o[3] = f2b(xv.w);
        *(u16x4*)(xb + (size_t)t * D_ + d) = o;
#pragma unroll
        for (int e = 0; e < E_; ++e) {
            float4 g = *(const float4*)&gws[e * D_ + d];
            part[e] += xv.x * g.x + xv.y * g.y + xv.z * g.z + xv.w * g.w;
        }
    }
#pragma unroll
    for (int off = 32; off >= 1; off >>= 1) {
#pragma unroll
        for (int e = 0; e < E_; ++e) part[e] += __shfl_xor(part[e], off);
    }
    if (lane == 0) {
        int e0 = 0; float m0 = part[0];
#pragma unroll
        for (int e = 1; e < E_; ++e) if (part[e] > m0) { m0 = part[e]; e0 = e; }
        int e1 = -1; float m1 = -3.4e38f;
#pragma unroll
        for (int e = 0; e < E_; ++e) if (e != e0 && part[e] > m1) { m1 = part[e]; e1 = e; }
        float sx = __expf(m1 - m0);
        float w0 = 1.f / (1.f + sx);
        float w1 = sx / (1.f + sx);
        int lp0 = atomicAdd(&cnt2[chunk * 16 + e0], 1);  // 16-int stride: 1 line/chunk
        int lp1 = atomicAdd(&cnt2[chunk * 16 + e1], 1);
        tslot[t] = make_int4(e0, lp0, e1, lp1);          // local record; fixup globalizes
        twgt[t] = make_float2(w0, w1);
    }
}

// ---- scan2: per-expert chunk prefix (exclusive), offs, cnt ----
__global__ void k_scan2(const int* __restrict__ cnt2, int* __restrict__ chunk_off,
                        int* __restrict__ cnt, int* __restrict__ offs) {
    __shared__ int totals[E_];
    int e = threadIdx.x >> 6, lane = threadIdx.x & 63;   // wave = expert
    int v = cnt2[lane * 16 + e];
    int incl = v;
#pragma unroll
    for (int d = 1; d < 64; d <<= 1) {
        int u = __shfl_up(incl, d);
        if (lane >= d) incl += u;
    }
    int excl = incl - v;
    if (lane == 63) totals[e] = incl;
    __syncthreads();
    chunk_off[lane * 8 + e] = excl;        // per-expert position base
    if (lane == 0) {
        int off_e = 0;
        for (int q = 0; q < e; ++q) off_e += totals[q];
        offs[e] = off_e; cnt[e] = totals[e];
    }
}

// ---- fixup: local slot -> per-expert slot; build tok lists ----
__global__ void k_fixup(const int* __restrict__ chunk_off, int4* __restrict__ tslot,
                        int* __restrict__ tok) {
    int t = blockIdx.x * 256 + threadIdx.x;
    int chunk = (t >> 2) & 63;
    int4 r = tslot[t];
    int s0 = chunk_off[chunk * 8 + r.x] + r.y;   // per-expert slot, < cnt[e]
    int s1 = chunk_off[chunk * 8 + r.z] + r.w;
    tok[r.x * T_ + s0] = t;
    tok[r.z * T_ + s1] = t;
    tslot[t] = make_int4(r.x, s0, r.z, s1);
}

// ---- merged transpose: fp32 [R][C] -> bf16 [C][R]; z = which*8 + e ----
__global__ void k_transpose_all(const float* __restrict__ W0, const float* __restrict__ W1,
                                const float* __restrict__ W2, u16* __restrict__ w0t,
                                u16* __restrict__ w1t, u16* __restrict__ w2t) {
    __shared__ float tile[64][67];
    int z = blockIdx.z, which = z >> 3, e = z & 7;
    const float* src; u16* dst; int R, C, c0, r0;
    if (which == 0)      { src = W0 + (size_t)e * D_ * H_; dst = w0t + (size_t)e * D_ * H_;
                           R = D_; C = H_; c0 = blockIdx.x * 64; r0 = blockIdx.y * 64; }
    else if (which == 1) { src = W1 + (size_t)e * D_ * H_; dst = w1t + (size_t)e * D_ * H_;
                           R = D_; C = H_; c0 = blockIdx.x * 64; r0 = blockIdx.y * 64; }
    else                 { src = W2 + (size_t)e * H_ * D_; dst = w2t + (size_t)e * H_ * D_;
                           R = H_; C = D_; c0 = blockIdx.y * 64; r0 = blockIdx.x * 64; }
    int tc4 = (threadIdx.x & 15) * 4, tr = threadIdx.x >> 4;
#pragma unroll
    for (int p = 0; p < 4; ++p) {
        float4 v = *(const float4*)(src + (size_t)(r0 + tr + 16 * p) * C + c0 + tc4);
        tile[tr + 16 * p][tc4 + 0] = v.x;
        tile[tr + 16 * p][tc4 + 1] = v.y;
        tile[tr + 16 * p][tc4 + 2] = v.z;
        tile[tr + 16 * p][tc4 + 3] = v.w;
    }
    __syncthreads();
    int r4 = (threadIdx.x & 15) * 4, tc = threadIdx.x >> 4;
#pragma unroll
    for (int p = 0; p < 4; ++p) {
        int c = tc + 16 * p;
        u16x4 o;
#pragma unroll
        for (int j = 0; j < 4; ++j) o[j] = f2b(tile[r4 + j][c]);
        *(u16x4*)(dst + (size_t)(c0 + c) * R + r0 + r4) = o;
    }
}

// ---- GEMM1: BM=256, BN=256={W0,W1} interleaved/32 cols (r14-validated layout),
//      4 fine phases/K-tile, counted vmcnt(4), dbuf 2x64KB. 8 waves 2Mx4N. ----
__launch_bounds__(512, 2)
__global__ void k_gemm1(const u16* __restrict__ xb, const u16* __restrict__ w0t,
                        const u16* __restrict__ w1t, const float* __restrict__ b0,
                        const float* __restrict__ b1, const int* __restrict__ tok,
                        const int* __restrict__ cnt, const int* __restrict__ offs,
                        u16* __restrict__ gbuf) {
    int e = blockIdx.z, rt = blockIdx.y, ct = blockIdx.x;
    int cN = cnt[e];
    if (rt * 256 >= cN) return;
    __shared__ char lds[131072];  // slot s @ s*65536: A[256][64] @0, B[256][64] @32768
    int tid = threadIdx.x, wid = tid >> 6, lane = tid & 63;
    int wm = wid >> 2, wn = wid & 3;  // per-wave output: 128 rows x 64 cols
    const int* tokE = tok + e * T_;
    const u16* w0e = w0t + (size_t)e * H_ * D_;
    size_t wdelta = (size_t)(w1t - w0t);

    // A: chunk i covers rows 64i..64i+63. Group MH = {MH, MH+2} (rows bit6==MH).
    unsigned aoff[4]; int adst[4];
#pragma unroll
    for (int i = 0; i < 4; ++i) {
        int cid = i * 512 + tid;
        int r = cid >> 3, c = cid & 7, cc = c ^ (r & 7);
        int tk = tokE[min(rt * 256 + r, cN - 1)];
        aoff[i] = (unsigned)(tk * D_ + cc * 8);
        adst[i] = (i * 512 + wid * 64) * 16;
    }
    // B: group NH covers 32-row groups with bit5==NH. 2 chunks/thread per group.
    size_t boff[2][2]; int bdst[2][2];
#pragma unroll
    for (int NH = 0; NH < 2; ++NH)
#pragma unroll
        for (int l = 0; l < 2; ++l) {
            int c = l * 512 + tid;
            int rw = c >> 3;                       // 0..127
            int q = rw >> 5;                       // 0..3
            int rr = (q * 2 + NH) * 32 + (rw & 31);  // actual B row
            int cc = (c & 7) ^ (rr & 7);
            int g = rr >> 5, which = g & 1;
            int hcol = ct * 128 + (g >> 1) * 32 + (rr & 31);
            boff[NH][l] = (size_t)which * wdelta + (size_t)hcol * D_ + cc * 8;
            int rw0 = l * 64 + wid * 8;            // wave-lane0's rw
            int rr0 = ((rw0 >> 5) * 2 + NH) * 32 + (rw0 & 31);
            bdst[NH][l] = 32768 + rr0 * 128;       // wave-uniform base (lane*16 added by HW)
        }

    auto stA = [&](int MH, char* slot, int k0) {
        gld16(xb + aoff[MH] + k0, slot + adst[MH]);
        gld16(xb + aoff[MH + 2] + k0, slot + adst[MH + 2]);
    };
    auto stB = [&](int NH, char* slot, int k0) {
        gld16(w0e + boff[NH][0] + k0, slot + bdst[NH][0]);
        gld16(w0e + boff[NH][1] + k0, slot + bdst[NH][1]);
    };

    f32x4 acc[8][4];
#pragma unroll
    for (int m = 0; m < 8; ++m)
#pragma unroll
        for (int n = 0; n < 4; ++n) acc[m][n] = (f32x4)0.f;

    auto rdA = [&](const char* As, int MH, bf16x8 (&af)[2][4]) {
#pragma unroll
        for (int ks = 0; ks < 2; ++ks) {
            int kc = ks * 4 + (lane >> 4);
#pragma unroll
            for (int m = 0; m < 4; ++m) {
                int row = wm * 128 + MH * 64 + m * 16 + (lane & 15);
                af[ks][m] = *(const bf16x8*)(As + row * 128 + ((kc ^ (row & 7)) << 4));
            }
        }
    };
    auto rdB = [&](const char* Bs, int NH, bf16x8 (&bf)[2][2]) {
#pragma unroll
        for (int ks = 0; ks < 2; ++ks) {
            int kc = ks * 4 + (lane >> 4);
#pragma unroll
            for (int n = 0; n < 2; ++n) {
                int rb = wn * 64 + (NH * 2 + n) * 16 + (lane & 15);
                bf[ks][n] = *(const bf16x8*)(Bs + rb * 128 + ((kc ^ (rb & 7)) << 4));
            }
        }
    };
    auto mfma = [&](int MH, int NH, bf16x8 (&af)[2][4], bf16x8 (&bf)[2][2]) {
        __builtin_amdgcn_s_setprio(1);
#pragma unroll
        for (int ks = 0; ks < 2; ++ks)
#pragma unroll
            for (int m = 0; m < 4; ++m)
#pragma unroll
                for (int n = 0; n < 2; ++n)
                    acc[MH * 4 + m][NH * 2 + n] = __builtin_amdgcn_mfma_f32_16x16x32_bf16(
                        af[ks][m], bf[ks][n], acc[MH * 4 + m][NH * 2 + n], 0, 0, 0);
        __builtin_amdgcn_s_setprio(0);
    };

    const int NT = D_ / 64;
    // prologue: tile 0 into slot 0, order A0, B0, A1, B1 (2 loads each)
    stA(0, lds, 0); stB(0, lds, 0); stA(1, lds, 0); stB(1, lds, 0);
    for (int t = 0; t < NT; ++t) {
        char* As = lds + (t & 1) * 65536;
        char* Bs = As + 32768;
        char* Ns = lds + ((t + 1) & 1) * 65536;
        int k1 = (t + 1) * 64;
        bool pf = (t + 1 < NT);
        bf16x8 a0[2][4], a1[2][4], bq0[2][2], bq1[2][2];
        // p0 (0,0): needs A0,B0 (oldest 4 of this tile's 8)
        asm volatile("s_waitcnt vmcnt(4)" ::: "memory");
        __builtin_amdgcn_s_barrier();
        rdA(As, 0, a0); rdB(Bs, 0, bq0);
        if (pf) stA(0, Ns, k1);
        mfma(0, 0, a0, bq0);
        // p1 (1,0): needs A1
        if (pf) asm volatile("s_waitcnt vmcnt(4)" ::: "memory");
        else    asm volatile("s_waitcnt vmcnt(2)" ::: "memory");
        __builtin_amdgcn_s_barrier();
        rdA(As, 1, a1);
        if (pf) stB(0, Ns, k1);
        mfma(1, 0, a1, bq0);
        // p2 (0,1): needs B1
        if (pf) asm volatile("s_waitcnt vmcnt(4)" ::: "memory");
        else    asm volatile("s_waitcnt vmcnt(0)" ::: "memory");
        __builtin_amdgcn_s_barrier();
        rdB(Bs, 1, bq1);
        if (pf) stA(1, Ns, k1);
        mfma(0, 1, a0, bq1);
        // p3 (1,1): everything resident
        __builtin_amdgcn_s_barrier();
        if (pf) stB(1, Ns, k1);
        mfma(1, 1, a1, bq1);
    }

    int off_e = offs[e];
#pragma unroll
    for (int n = 0; n < 2; ++n) {
        int hc = ct * 128 + wn * 32 + n * 16 + (lane & 15);
        float bb0 = b0[e * H_ + hc], bb1 = b1[e * H_ + hc];
#pragma unroll
        for (int mi = 0; mi < 8; ++mi)
#pragma unroll
            for (int i = 0; i < 4; ++i) {
                int idx = rt * 256 + wm * 128 + mi * 16 + (lane >> 4) * 4 + i;
                if (idx < cN) {
                    float h0 = acc[mi][n][i] + bb0;      // W0 cols (frags 0-1)
                    float h1 = acc[mi][n + 2][i] + bb1;  // W1 cols (frags 2-3)
                    float g = h0 * h1 / (1.f + __expf(-h1));
                    gbuf[(size_t)(off_e + idx) * H_ + hc] = f2b(g);
                }
            }
    }
}

// ---- GEMM2 (round-12): g[128,2048] @ W2t[128-col tile] -> y bf16 (incl b2) ----
__launch_bounds__(256, 2)
__global__ void k_gemm2(const u16* __restrict__ gbuf, const u16* __restrict__ w2t,
                        const float* __restrict__ b2, const int* __restrict__ cnt,
                        const int* __restrict__ offs, u16* __restrict__ yb) {
    int e = blockIdx.z, rt = blockIdx.y, ct = blockIdx.x;
    int cN = cnt[e];
    if (rt * 128 >= cN) return;
    __shared__ u16 lds[16384];  // A:[128][64] @0, B:[128][64] @16KB (bytes)
    char* ldsB = (char*)lds;
    int tid = threadIdx.x, wid = tid >> 6, lane = tid & 63;
    int wm = wid >> 1, wn = wid & 1;
    int off_e = offs[e];
    const u16* Ag = gbuf + (size_t)(off_e + rt * 128) * H_;  // padded tail allows over-read
    const u16* Bw = w2t + (size_t)e * D_ * H_ + (size_t)(ct * 128) * H_;

    size_t soff[4]; int sdst[4];
#pragma unroll
    for (int p = 0; p < 4; ++p) {
        int cid = p * 256 + tid, r = cid >> 3, c = cid & 7;
        int cc = c ^ (r & 7);
        soff[p] = (size_t)r * H_ + cc * 8;
        sdst[p] = (p * 256 + wid * 64) * 16;
    }
    f32x4 acc[4][4];
#pragma unroll
    for (int m = 0; m < 4; ++m)
#pragma unroll
        for (int n = 0; n < 4; ++n) acc[m][n] = (f32x4)0.f;

    for (int kt = 0; kt < H_ / 64; ++kt) {
        int k0 = kt * 64;
        __syncthreads();
#pragma unroll
        for (int p = 0; p < 4; ++p) gld16(Ag + soff[p] + k0, ldsB + sdst[p]);
#pragma unroll
        for (int p = 0; p < 4; ++p) gld16(Bw + soff[p] + k0, ldsB + 16384 + sdst[p]);
        __syncthreads();
#pragma unroll
        for (int ks = 0; ks < 2; ++ks) {
            int kc = ks * 4 + (lane >> 4);
            bf16x8 af[4], bfr[4];
#pragma unroll
            for (int m = 0; m < 4; ++m) {
                int row = wm * 64 + m * 16 + (lane & 15);
                af[m] = *(const bf16x8*)(ldsB + row * 128 + ((kc ^ (row & 7)) << 4));
            }
#pragma unroll
            for (int n = 0; n < 4; ++n) {
                int nr = wn * 64 + n * 16 + (lane & 15);
                bfr[n] = *(const bf16x8*)(ldsB + 16384 + nr * 128 + ((kc ^ (nr & 7)) << 4));
            }
#pragma unroll
            for (int m = 0; m < 4; ++m)
#pragma unroll
                for (int n = 0; n < 4; ++n)
                    acc[m][n] = __builtin_amdgcn_mfma_f32_16x16x32_bf16(af[m], bfr[n], acc[m][n], 0, 0, 0);
        }
    }
    const float* b2e = b2 + e * D_;
#pragma unroll
    for (int m = 0; m < 4; ++m)
#pragma unroll
        for (int i = 0; i < 4; ++i) {
            int row = wm * 64 + m * 16 + (lane >> 4) * 4 + i;
            int idx = rt * 128 + row;
            if (idx < cN) {
#pragma unroll
                for (int n = 0; n < 4; ++n) {
                    int dc = ct * 128 + wn * 64 + n * 16 + (lane & 15);
                    yb[(size_t)(off_e + idx) * D_ + dc] = f2b(acc[m][n][i] + b2e[dc]);
                }
            }
        }
}

// ---- combine: out[t] = w0*y[offs[e0]+slot0] + w1*y[offs[e1]+slot1] ----
__global__ void k_combine(const u16* __restrict__ yb, const int4* __restrict__ tslot,
                          const float2* __restrict__ twgt, const int* __restrict__ offs,
                          float* __restrict__ out) {
    int t = blockIdx.x, d4 = threadIdx.x * 4;
    int4 s = tslot[t];
    float2 w = twgt[t];
    const u16* y0 = yb + (size_t)(offs[s.x] + s.y) * D_ + d4;
    const u16* y1 = yb + (size_t)(offs[s.z] + s.w) * D_ + d4;
    u16x4 a = *(const u16x4*)y0;
    u16x4 b = *(const u16x4*)y1;
    float4 o;
    o.x = w.x * b2f(a[0]) + w.y * b2f(b[0]);
    o.y = w.x * b2f(a[1]) + w.y * b2f(b[1]);
    o.z = w.x * b2f(a[2]) + w.y * b2f(b[2]);
    o.w = w.x * b2f(a[3]) + w.y * b2f(b[3]);
    *(float4*)(out + (size_t)t * D_ + d4) = o;
}

extern "C" void kernel_launch(void* const* d_in, const int* in_sizes, int n_in,
                              void* d_out, int out_size, void* d_ws, size_t ws_size,
                              hipStream_t stream) {
    const float* x  = (const float*)d_in[0];
    const float* gw = (const float*)d_in[1];
    const float* W0 = (const float*)d_in[2];
    const float* b0 = (const float*)d_in[3];
    const float* W1 = (const float*)d_in[4];
    const float* b1 = (const float*)d_in[5];
    const float* W2 = (const float*)d_in[6];
    const float* b2 = (const float*)d_in[7];
    float* out = (float*)d_out;

    char* ws = (char*)d_ws;
    size_t off = 0;
    u16* xb   = (u16*)(ws + off); off += (size_t)T_ * D_ * 2;             // 8 MB
    u16* w0t  = (u16*)(ws + off); off += (size_t)E_ * H_ * D_ * 2;        // 32 MB
    u16* w1t  = (u16*)(ws + off); off += (size_t)E_ * H_ * D_ * 2;        // 32 MB (contiguous after w0t)
    u16* w2t  = (u16*)(ws + off); off += (size_t)E_ * D_ * H_ * 2;        // 32 MB
    u16* gbuf = (u16*)(ws + off); off += (size_t)(T_ * 2 + 256) * H_ * 2; // padded tail
    int*   tok   = (int*)(ws + off);    off += (size_t)E_ * T_ * 4;
    int4*  tslot = (int4*)(ws + off);   off += (size_t)T_ * 16;
    float2* twgt = (float2*)(ws + off); off += (size_t)T_ * 8;
    int*   cnt2  = (int*)(ws + off);    off += 64 * 16 * 4;   // 64 chunks x 1 line
    int*   choff = (int*)(ws + off);    off += 64 * 8 * 4;
    int*   cnt   = (int*)(ws + off);    off += 64;
    int*   offs  = (int*)(ws + off);    off += 64;
    // y reuses w0t's region (dead after gemm1; gemm2 runs strictly after gemm1)
    u16* yb = w0t;  // needs (2T+256)*D*2 = 17 MB <= 32 MB

    if (ws_size < off) return;  // workspace too small: leave output poisoned (visible failure)
    hipMemsetAsync(cnt2, 0, 64 * 16 * 4, stream);

    k_gate<<<T_ / 4, 256, 0, stream>>>(x, gw, cnt2, tslot, twgt, xb);
    k_scan2<<<1, 512, 0, stream>>>(cnt2, choff, cnt, offs);
    k_fixup<<<T_ / 256, 256, 0, stream>>>(choff, tslot, tok);
    k_transpose_all<<<dim3(32, 16, 24), 256, 0, stream>>>(W0, W1, W2, w0t, w1t, w2t);
    k_gemm1<<<dim3(H_ / 128, T_ / 256, E_), 512, 0, stream>>>(xb, w0t, w1t, b0, b1, tok, cnt, offs, gbuf);
    k_gemm2<<<dim3(D_ / 128, T_ / 128, E_), 256, 0, stream>>>(gbuf, w2t, b2, cnt, offs, yb);
    k_combine<<<T_, 256, 0, stream>>>(yb, tslot, twgt, offs, out);
}

// Round 16
// 231.953 us; speedup vs baseline: 1.1573x; 1.0824x over previous
//
#include <hip/hip_runtime.h>
#include <hip/hip_bf16.h>
#include <cstdint>

// MoE SwiGLU: E=8 experts, top-2, D=1024, H=2048, T=4096 tokens.
// Round 16: consolidation. gemm1/gemm2 = round-12 (proven best: 2-barrier
// 128-tile, 687 TF — 8 schedule-rewrite attempts all regressed; stopping).
// Gate merged into the transpose launch (k_prep): gate compute hides under
// the transpose's HBM-roofline time on the serial stream.

#define E_ 8
#define D_ 1024
#define H_ 2048
#define T_ 4096

typedef __attribute__((ext_vector_type(8))) __bf16 bf16x8;
typedef __attribute__((ext_vector_type(4))) float f32x4;
typedef unsigned short u16;
typedef __attribute__((ext_vector_type(4))) u16 u16x4;

__device__ __forceinline__ u16 f2b(float f) {
    union { float f; unsigned int u; } v; v.f = f;
    unsigned int u = v.u;
    return (u16)((u + 0x7FFFu + ((u >> 16) & 1u)) >> 16);  // RNE
}

__device__ __forceinline__ float b2f(u16 v) {
    union { unsigned int u; float f; } x; x.u = (unsigned int)v << 16; return x.f;
}

__device__ __forceinline__ void gld16(const void* g, void* l) {
    __builtin_amdgcn_global_load_lds((const __attribute__((address_space(1))) void*)g,
                                     (__attribute__((address_space(3))) void*)l, 16, 0, 0);
}

// ---- k_prep: merged {weight transpose+cvt} and {gate}. grid (32,16,26). ----
// z<24: transpose slice (which=z>>3, e=z&7). z>=24: gate block
// gb=(z-24)*512+y*32+x in [0,1024), 1 token/wave, gw LDS-cached, chunked cnt.
__global__ void k_prep(const float* __restrict__ W0, const float* __restrict__ W1,
                       const float* __restrict__ W2, u16* __restrict__ w0t,
                       u16* __restrict__ w1t, u16* __restrict__ w2t,
                       const float* __restrict__ x, const float* __restrict__ gw,
                       int* __restrict__ cnt2, int4* __restrict__ tslot,
                       float2* __restrict__ twgt, u16* __restrict__ xb) {
    __shared__ __align__(16) char smem[32768];
    int z = blockIdx.z;
    int tid = threadIdx.x;
    if (z < 24) {
        // ---------- transpose path: fp32 [R][C] -> bf16 [C][R] ----------
        float (*tile)[67] = (float(*)[67])smem;  // 64x67 = 17KB
        int which = z >> 3, e = z & 7;
        const float* src; u16* dst; int R, C, c0, r0;
        if (which == 0)      { src = W0 + (size_t)e * D_ * H_; dst = w0t + (size_t)e * D_ * H_;
                               R = D_; C = H_; c0 = blockIdx.x * 64; r0 = blockIdx.y * 64; }
        else if (which == 1) { src = W1 + (size_t)e * D_ * H_; dst = w1t + (size_t)e * D_ * H_;
                               R = D_; C = H_; c0 = blockIdx.x * 64; r0 = blockIdx.y * 64; }
        else                 { src = W2 + (size_t)e * H_ * D_; dst = w2t + (size_t)e * H_ * D_;
                               R = H_; C = D_; c0 = blockIdx.y * 64; r0 = blockIdx.x * 64; }
        int tc4 = (tid & 15) * 4, tr = tid >> 4;
#pragma unroll
        for (int p = 0; p < 4; ++p) {
            float4 v = *(const float4*)(src + (size_t)(r0 + tr + 16 * p) * C + c0 + tc4);
            tile[tr + 16 * p][tc4 + 0] = v.x;
            tile[tr + 16 * p][tc4 + 1] = v.y;
            tile[tr + 16 * p][tc4 + 2] = v.z;
            tile[tr + 16 * p][tc4 + 3] = v.w;
        }
        __syncthreads();
        int r4 = (tid & 15) * 4, tc = tid >> 4;
#pragma unroll
        for (int p = 0; p < 4; ++p) {
            int c = tc + 16 * p;
            u16x4 o;
#pragma unroll
            for (int j = 0; j < 4; ++j) o[j] = f2b(tile[r4 + j][c]);
            *(u16x4*)(dst + (size_t)(c0 + c) * R + r0 + r4) = o;
        }
    } else {
        // ---------- gate path ----------
        float* gws = (float*)smem;  // 8192 floats = 32KB
        int gb = (z - 24) * 512 + blockIdx.y * 32 + blockIdx.x;  // 0..1023
#pragma unroll
        for (int p = 0; p < 8; ++p) {
            int i = (p * 256 + tid) * 4;
            *(float4*)&gws[i] = *(const float4*)&gw[i];
        }
        __syncthreads();
        int wid = tid >> 6, lane = tid & 63;
        int t = gb * 4 + wid;
        int chunk = gb & 63;
        const float* xr = x + (size_t)t * D_;
        float part[E_];
#pragma unroll
        for (int e = 0; e < E_; ++e) part[e] = 0.f;
#pragma unroll
        for (int i = 0; i < 4; ++i) {
            int d = i * 256 + lane * 4;
            float4 xv = *(const float4*)(xr + d);
            u16x4 o;
            o[0] = f2b(xv.x); o[1] = f2b(xv.y); o[2] = f2b(xv.z); o[3] = f2b(xv.w);
            *(u16x4*)(xb + (size_t)t * D_ + d) = o;
#pragma unroll
            for (int e = 0; e < E_; ++e) {
                float4 g = *(const float4*)&gws[e * D_ + d];
                part[e] += xv.x * g.x + xv.y * g.y + xv.z * g.z + xv.w * g.w;
            }
        }
#pragma unroll
        for (int off = 32; off >= 1; off >>= 1) {
#pragma unroll
            for (int e = 0; e < E_; ++e) part[e] += __shfl_xor(part[e], off);
        }
        if (lane == 0) {
            int e0 = 0; float m0 = part[0];
#pragma unroll
            for (int e = 1; e < E_; ++e) if (part[e] > m0) { m0 = part[e]; e0 = e; }
            int e1 = -1; float m1 = -3.4e38f;
#pragma unroll
            for (int e = 0; e < E_; ++e) if (e != e0 && part[e] > m1) { m1 = part[e]; e1 = e; }
            float sx = __expf(m1 - m0);
            float w0 = 1.f / (1.f + sx);
            float w1 = sx / (1.f + sx);
            int lp0 = atomicAdd(&cnt2[chunk * 16 + e0], 1);  // 1 cache line per chunk
            int lp1 = atomicAdd(&cnt2[chunk * 16 + e1], 1);
            tslot[t] = make_int4(e0, lp0, e1, lp1);
            twgt[t] = make_float2(w0, w1);
        }
    }
}

// ---- scan2: per-expert chunk prefix (exclusive), offs, cnt ----
__global__ void k_scan2(const int* __restrict__ cnt2, int* __restrict__ chunk_off,
                        int* __restrict__ cnt, int* __restrict__ offs) {
    __shared__ int totals[E_];
    int e = threadIdx.x >> 6, lane = threadIdx.x & 63;   // wave = expert
    int v = cnt2[lane * 16 + e];
    int incl = v;
#pragma unroll
    for (int d = 1; d < 64; d <<= 1) {
        int u = __shfl_up(incl, d);
        if (lane >= d) incl += u;
    }
    int excl = incl - v;
    if (lane == 63) totals[e] = incl;
    __syncthreads();
    chunk_off[lane * 8 + e] = excl;        // per-expert position base
    if (lane == 0) {
        int off_e = 0;
        for (int q = 0; q < e; ++q) off_e += totals[q];
        offs[e] = off_e; cnt[e] = totals[e];
    }
}

// ---- fixup: local slot -> per-expert slot; build tok lists ----
__global__ void k_fixup(const int* __restrict__ chunk_off, int4* __restrict__ tslot,
                        int* __restrict__ tok) {
    int t = blockIdx.x * 256 + threadIdx.x;
    int chunk = (t >> 2) & 63;
    int4 r = tslot[t];
    int s0 = chunk_off[chunk * 8 + r.x] + r.y;   // per-expert slot, < cnt[e]
    int s1 = chunk_off[chunk * 8 + r.z] + r.w;
    tok[r.x * T_ + s0] = t;
    tok[r.z * T_ + s1] = t;
    tslot[t] = make_int4(r.x, s0, r.z, s1);
}

// ---- GEMM1 (round-12): gathered X[128,1024] @ {W0t,W1t}[64-col tile] ----
__launch_bounds__(256, 2)
__global__ void k_gemm1(const u16* __restrict__ xb, const u16* __restrict__ w0t,
                        const u16* __restrict__ w1t, const float* __restrict__ b0,
                        const float* __restrict__ b1, const int* __restrict__ tok,
                        const int* __restrict__ cnt, const int* __restrict__ offs,
                        u16* __restrict__ gbuf) {
    int e = blockIdx.z, rt = blockIdx.y, ct = blockIdx.x;
    int cN = cnt[e];
    if (rt * 128 >= cN) return;
    __shared__ u16 lds[16384];  // A:[128][64] @0, B0:[64][64] @16KB, B1 @24KB (bytes)
    char* ldsB = (char*)lds;
    int tid = threadIdx.x, wid = tid >> 6, lane = tid & 63;
    int wm = wid >> 1, wn = wid & 1;
    const int* tokE = tok + e * T_;
    const u16* w0e = w0t + (size_t)e * H_ * D_;
    const u16* w1e = w1t + (size_t)e * H_ * D_;

    size_t aoff[4]; int adst[4];
#pragma unroll
    for (int p = 0; p < 4; ++p) {
        int cid = p * 256 + tid, r = cid >> 3, c = cid & 7;
        int cc = c ^ (r & 7);                       // pre-swizzled source chunk
        int tk = tokE[min(rt * 128 + r, cN - 1)];   // gather (clamped padding)
        aoff[p] = (size_t)tk * D_ + cc * 8;
        adst[p] = (p * 256 + wid * 64) * 16;
    }
    size_t boff[2]; int bdst[2];
#pragma unroll
    for (int p = 0; p < 2; ++p) {
        int cid = p * 256 + tid, n = cid >> 3, c = cid & 7;
        int cc = c ^ (n & 7);
        boff[p] = (size_t)(ct * 64 + n) * D_ + cc * 8;
        bdst[p] = (p * 256 + wid * 64) * 16;
    }

    f32x4 acc0[4][2], acc1[4][2];
#pragma unroll
    for (int m = 0; m < 4; ++m)
#pragma unroll
        for (int n = 0; n < 2; ++n) { acc0[m][n] = (f32x4)0.f; acc1[m][n] = (f32x4)0.f; }

    for (int kt = 0; kt < D_ / 64; ++kt) {
        int k0 = kt * 64;
        __syncthreads();
#pragma unroll
        for (int p = 0; p < 4; ++p) gld16(xb + aoff[p] + k0, ldsB + adst[p]);
#pragma unroll
        for (int p = 0; p < 2; ++p) gld16(w0e + boff[p] + k0, ldsB + 16384 + bdst[p]);
#pragma unroll
        for (int p = 0; p < 2; ++p) gld16(w1e + boff[p] + k0, ldsB + 24576 + bdst[p]);
        __syncthreads();
#pragma unroll
        for (int ks = 0; ks < 2; ++ks) {
            int kc = ks * 4 + (lane >> 4);
            bf16x8 af[4], b0f[2], b1f[2];
#pragma unroll
            for (int m = 0; m < 4; ++m) {
                int row = wm * 64 + m * 16 + (lane & 15);
                af[m] = *(const bf16x8*)(ldsB + row * 128 + ((kc ^ (row & 7)) << 4));
            }
#pragma unroll
            for (int n = 0; n < 2; ++n) {
                int nr = wn * 32 + n * 16 + (lane & 15);
                int so = (kc ^ (nr & 7)) << 4;
                b0f[n] = *(const bf16x8*)(ldsB + 16384 + nr * 128 + so);
                b1f[n] = *(const bf16x8*)(ldsB + 24576 + nr * 128 + so);
            }
#pragma unroll
            for (int m = 0; m < 4; ++m)
#pragma unroll
                for (int n = 0; n < 2; ++n) {
                    acc0[m][n] = __builtin_amdgcn_mfma_f32_16x16x32_bf16(af[m], b0f[n], acc0[m][n], 0, 0, 0);
                    acc1[m][n] = __builtin_amdgcn_mfma_f32_16x16x32_bf16(af[m], b1f[n], acc1[m][n], 0, 0, 0);
                }
        }
    }
    int off_e = offs[e];
    const float* b0e = b0 + e * H_;
    const float* b1e = b1 + e * H_;
#pragma unroll
    for (int n = 0; n < 2; ++n) {
        int hc = ct * 64 + wn * 32 + n * 16 + (lane & 15);
        float bb0 = b0e[hc], bb1 = b1e[hc];
#pragma unroll
        for (int m = 0; m < 4; ++m)
#pragma unroll
            for (int i = 0; i < 4; ++i) {
                int row = wm * 64 + m * 16 + (lane >> 4) * 4 + i;
                int idx = rt * 128 + row;
                if (idx < cN) {
                    float h0 = acc0[m][n][i] + bb0;
                    float h1 = acc1[m][n][i] + bb1;
                    float g = h0 * h1 / (1.f + __expf(-h1));
                    gbuf[(size_t)(off_e + idx) * H_ + hc] = f2b(g);
                }
            }
    }
}

// ---- GEMM2 (round-12): g[128,2048] @ W2t[128-col tile] -> y bf16 (incl b2) ----
__launch_bounds__(256, 2)
__global__ void k_gemm2(const u16* __restrict__ gbuf, const u16* __restrict__ w2t,
                        const float* __restrict__ b2, const int* __restrict__ cnt,
                        const int* __restrict__ offs, u16* __restrict__ yb) {
    int e = blockIdx.z, rt = blockIdx.y, ct = blockIdx.x;
    int cN = cnt[e];
    if (rt * 128 >= cN) return;
    __shared__ u16 lds[16384];  // A:[128][64] @0, B:[128][64] @16KB (bytes)
    char* ldsB = (char*)lds;
    int tid = threadIdx.x, wid = tid >> 6, lane = tid & 63;
    int wm = wid >> 1, wn = wid & 1;
    int off_e = offs[e];
    const u16* Ag = gbuf + (size_t)(off_e + rt * 128) * H_;  // padded tail allows over-read
    const u16* Bw = w2t + (size_t)e * D_ * H_ + (size_t)(ct * 128) * H_;

    size_t soff[4]; int sdst[4];
#pragma unroll
    for (int p = 0; p < 4; ++p) {
        int cid = p * 256 + tid, r = cid >> 3, c = cid & 7;
        int cc = c ^ (r & 7);
        soff[p] = (size_t)r * H_ + cc * 8;
        sdst[p] = (p * 256 + wid * 64) * 16;
    }
    f32x4 acc[4][4];
#pragma unroll
    for (int m = 0; m < 4; ++m)
#pragma unroll
        for (int n = 0; n < 4; ++n) acc[m][n] = (f32x4)0.f;

    for (int kt = 0; kt < H_ / 64; ++kt) {
        int k0 = kt * 64;
        __syncthreads();
#pragma unroll
        for (int p = 0; p < 4; ++p) gld16(Ag + soff[p] + k0, ldsB + sdst[p]);
#pragma unroll
        for (int p = 0; p < 4; ++p) gld16(Bw + soff[p] + k0, ldsB + 16384 + sdst[p]);
        __syncthreads();
#pragma unroll
        for (int ks = 0; ks < 2; ++ks) {
            int kc = ks * 4 + (lane >> 4);
            bf16x8 af[4], bfr[4];
#pragma unroll
            for (int m = 0; m < 4; ++m) {
                int row = wm * 64 + m * 16 + (lane & 15);
                af[m] = *(const bf16x8*)(ldsB + row * 128 + ((kc ^ (row & 7)) << 4));
            }
#pragma unroll
            for (int n = 0; n < 4; ++n) {
                int nr = wn * 64 + n * 16 + (lane & 15);
                bfr[n] = *(const bf16x8*)(ldsB + 16384 + nr * 128 + ((kc ^ (nr & 7)) << 4));
            }
#pragma unroll
            for (int m = 0; m < 4; ++m)
#pragma unroll
                for (int n = 0; n < 4; ++n)
                    acc[m][n] = __builtin_amdgcn_mfma_f32_16x16x32_bf16(af[m], bfr[n], acc[m][n], 0, 0, 0);
        }
    }
    const float* b2e = b2 + e * D_;
#pragma unroll
    for (int m = 0; m < 4; ++m)
#pragma unroll
        for (int i = 0; i < 4; ++i) {
            int row = wm * 64 + m * 16 + (lane >> 4) * 4 + i;
            int idx = rt * 128 + row;
            if (idx < cN) {
#pragma unroll
                for (int n = 0; n < 4; ++n) {
                    int dc = ct * 128 + wn * 64 + n * 16 + (lane & 15);
                    yb[(size_t)(off_e + idx) * D_ + dc] = f2b(acc[m][n][i] + b2e[dc]);
                }
            }
        }
}

// ---- combine: out[t] = w0*y[offs[e0]+slot0] + w1*y[offs[e1]+slot1] ----
__global__ void k_combine(const u16* __restrict__ yb, const int4* __restrict__ tslot,
                          const float2* __restrict__ twgt, const int* __restrict__ offs,
                          float* __restrict__ out) {
    int t = blockIdx.x, d4 = threadIdx.x * 4;
    int4 s = tslot[t];
    float2 w = twgt[t];
    const u16* y0 = yb + (size_t)(offs[s.x] + s.y) * D_ + d4;
    const u16* y1 = yb + (size_t)(offs[s.z] + s.w) * D_ + d4;
    u16x4 a = *(const u16x4*)y0;
    u16x4 b = *(const u16x4*)y1;
    float4 o;
    o.x = w.x * b2f(a[0]) + w.y * b2f(b[0]);
    o.y = w.x * b2f(a[1]) + w.y * b2f(b[1]);
    o.z = w.x * b2f(a[2]) + w.y * b2f(b[2]);
    o.w = w.x * b2f(a[3]) + w.y * b2f(b[3]);
    *(float4*)(out + (size_t)t * D_ + d4) = o;
}

extern "C" void kernel_launch(void* const* d_in, const int* in_sizes, int n_in,
                              void* d_out, int out_size, void* d_ws, size_t ws_size,
                              hipStream_t stream) {
    const float* x  = (const float*)d_in[0];
    const float* gw = (const float*)d_in[1];
    const float* W0 = (const float*)d_in[2];
    const float* b0 = (const float*)d_in[3];
    const float* W1 = (const float*)d_in[4];
    const float* b1 = (const float*)d_in[5];
    const float* W2 = (const float*)d_in[6];
    const float* b2 = (const float*)d_in[7];
    float* out = (float*)d_out;

    char* ws = (char*)d_ws;
    size_t off = 0;
    u16* xb   = (u16*)(ws + off); off += (size_t)T_ * D_ * 2;             // 8 MB
    u16* w0t  = (u16*)(ws + off); off += (size_t)E_ * H_ * D_ * 2;        // 32 MB
    u16* w1t  = (u16*)(ws + off); off += (size_t)E_ * H_ * D_ * 2;        // 32 MB
    u16* w2t  = (u16*)(ws + off); off += (size_t)E_ * D_ * H_ * 2;        // 32 MB
    u16* gbuf = (u16*)(ws + off); off += (size_t)(T_ * 2 + 256) * H_ * 2; // padded tail
    int*   tok   = (int*)(ws + off);    off += (size_t)E_ * T_ * 4;
    int4*  tslot = (int4*)(ws + off);   off += (size_t)T_ * 16;
    float2* twgt = (float2*)(ws + off); off += (size_t)T_ * 8;
    int*   cnt2  = (int*)(ws + off);    off += 64 * 16 * 4;   // 64 chunks x 1 line
    int*   choff = (int*)(ws + off);    off += 64 * 8 * 4;
    int*   cnt   = (int*)(ws + off);    off += 64;
    int*   offs  = (int*)(ws + off);    off += 64;
    // y reuses w0t's region (dead after gemm1; gemm2 runs strictly after gemm1)
    u16* yb = w0t;  // needs (2T+256)*D*2 = 17 MB <= 32 MB

    if (ws_size < off) return;  // workspace too small: leave output poisoned (visible failure)
    hipMemsetAsync(cnt2, 0, 64 * 16 * 4, stream);

    k_prep<<<dim3(32, 16, 26), 256, 0, stream>>>(W0, W1, W2, w0t, w1t, w2t,
                                                 x, gw, cnt2, tslot, twgt, xb);
    k_scan2<<<1, 512, 0, stream>>>(cnt2, choff, cnt, offs);
    k_fixup<<<T_ / 256, 256, 0, stream>>>(choff, tslot, tok);
    k_gemm1<<<dim3(H_ / 64, T_ / 128, E_), 256, 0, stream>>>(xb, w0t, w1t, b0, b1, tok, cnt, offs, gbuf);
    k_gemm2<<<dim3(D_ / 128, T_ / 128, E_), 256, 0, stream>>>(gbuf, w2t, b2, cnt, offs, yb);
    k_combine<<<T_, 256, 0, stream>>>(yb, tslot, twgt, offs, out);
}